// Round 9
// baseline (684.318 us; speedup 1.0000x reference)
//
#include <hip/hip_runtime.h>
#include <stdint.h>

#define T_LEN    1048576
#define TY_LEN   1048561
#define OUT_W    1048562
#define NM       32
#define WIN      16
#define NCH      4096
#define CL       256
#define TO       512    // outputs per conv block (2 per thread: t, t+256)
#define XS_W     528    // TO + 16 halo/pad -> LDS = 32*528*4 = 67584 B (2 blocks/CU)

__device__ inline float sgnf(float a){
    return (a > 0.0f) ? 1.0f : ((a < 0.0f) ? -1.0f : 0.0f);
}

// ---------------- transpose w[o][i][h] -> wT[h][i][o] (o fastest, for
// wave-uniform consecutive scalar loads in the conv inner loop)
__global__ void wtrans_kernel(const float* __restrict__ w, float* __restrict__ wT){
    const int idx = blockIdx.x * 256 + threadIdx.x;
    if (idx >= NM * NM * WIN) return;
    const int o = idx / (NM * WIN);
    const int r = idx - o * (NM * WIN);
    const int i = r / WIN;
    const int h = r - i * WIN;
    wT[(h * NM + i) * NM + o] = w[idx];
}

// ---------------- conv, XLA-CPU-faithful order (h-major, i-minor, bias last):
// per output (o,t): acc = 0; for h: for i: acc = fmaf(w[o][i][h], x[i][t+h], acc)
// 2 timesteps per thread: each 128 B weight s_load feeds 128 FMA-cycles
// (accA + accB), halving SMEM rate and per-FMA latency exposure vs 1-t.
// Per-accumulator FMA order is bit-identical to the passing kernels.
__global__ __launch_bounds__(256) void conv_kernel(
    const float* __restrict__ x, const float* __restrict__ wT,
    const float* __restrict__ b, float* __restrict__ out)
{
    __shared__ float xs[NM * XS_W];
    const int base = blockIdx.x * TO;
#pragma unroll 1
    for (int i = 0; i < NM; ++i) {
        for (int j = threadIdx.x; j < XS_W; j += 256) {
            const int t = base + j;
            xs[i * XS_W + j] = (j < TO + WIN - 1 && t < T_LEN) ? x[i * T_LEN + t] : 0.0f;
        }
    }
    __syncthreads();
    const int tl = threadIdx.x;
    float accA[NM], accB[NM];
#pragma unroll
    for (int o = 0; o < NM; ++o) { accA[o] = 0.0f; accB[o] = 0.0f; }
#pragma unroll 1
    for (int h = 0; h < WIN; ++h) {
        float xva[NM], xvb[NM];
#pragma unroll
        for (int i = 0; i < NM; ++i) {
            xva[i] = xs[i * XS_W + tl + h];
            xvb[i] = xs[i * XS_W + tl + 256 + h];
        }
#pragma unroll
        for (int i = 0; i < NM; ++i) {
            const float* wrow = wT + (h * NM + i) * NM;   // lane-uniform s_load
#pragma unroll
            for (int o = 0; o < NM; ++o) {
                accA[o] = fmaf(wrow[o], xva[i], accA[o]);
                accB[o] = fmaf(wrow[o], xvb[i], accB[o]);
            }
        }
    }
    const int ta = base + tl;
    const int tb = ta + 256;
#pragma unroll
    for (int o = 0; o < NM; ++o) {
        const float bv = b[o];
        if (ta < TY_LEN) out[(size_t)o * OUT_W + 1 + ta] = accA[o] + bv;
        if (tb < TY_LEN) out[(size_t)o * OUT_W + 1 + tb] = accB[o] + bv;
    }
}

// ---------------- pass A: per-(market, chunk) 4-candidate transition map
// candidates: {-1, 0, +1, start_pos}; exit quantized to {0,1,2} = {-1,0,+1}
__global__ __launch_bounds__(256) void scan_pass_a(
    const float* __restrict__ yb, const float* __restrict__ sp,
    const float* __restrict__ pwv, uint32_t* __restrict__ trans)
{
    const int gid = blockIdx.x * 256 + threadIdx.x;
    const int m = gid >> 12;
    const int c = gid & (NCH - 1);
    const float pw = pwv[m];
    float p0 = -1.0f, p1 = 0.0f, p2 = 1.0f, p3 = sp[m];
    const float* hr = yb + (size_t)m * OUT_W + 1 + c * CL;
    const int limit0 = TY_LEN - c * CL;
    const int limit = limit0 < CL ? limit0 : CL;
    int j = 0;
    for (; j + 4 <= limit; j += 4) {
        const float4 h = *reinterpret_cast<const float4*>(hr + j);
#define STEPA(hv) { const float hv_ = (hv); \
        p0 = sgnf(fmaf(p0, pw, hv_)); \
        p1 = sgnf(fmaf(p1, pw, hv_)); \
        p2 = sgnf(fmaf(p2, pw, hv_)); \
        p3 = sgnf(fmaf(p3, pw, hv_)); }
        STEPA(h.x); STEPA(h.y); STEPA(h.z); STEPA(h.w);
    }
    for (; j < limit; ++j) { STEPA(hr[j]); }
#undef STEPA
    const uint32_t e0 = (uint32_t)((int)p0 + 1);
    const uint32_t e1 = (uint32_t)((int)p1 + 1);
    const uint32_t e2 = (uint32_t)((int)p2 + 1);
    const uint32_t e3 = (uint32_t)((int)p3 + 1);
    trans[m * NCH + c] = e0 | (e1 << 8) | (e2 << 16) | (e3 << 24);
}

// ---------------- pass B: compose maps per market, emit entry state per chunk
__device__ inline uint32_t map_comp(uint32_t f, uint32_t g){
    uint32_t r = 0;
#pragma unroll
    for (int k = 0; k < 4; ++k) {
        const uint32_t s = (g >> (8 * k)) & 0xFFu;
        const uint32_t o = (f >> (8 * s)) & 0xFFu;
        r |= o << (8 * k);
    }
    return r;
}

__global__ __launch_bounds__(256) void scan_pass_b(
    const uint32_t* __restrict__ trans, uint8_t* __restrict__ entries)
{
    const uint32_t ID = 0x03020100u;   // identity; state 3 = raw start_pos
    const int m = blockIdx.x;
    const int tid = threadIdx.x;
    __shared__ uint32_t S[256];
    uint32_t maps[16];
    uint32_t seg = ID;
    const uint32_t* tr = trans + m * NCH + tid * 16;
#pragma unroll
    for (int j = 0; j < 16; ++j) { maps[j] = tr[j]; seg = map_comp(maps[j], seg); }
    S[tid] = seg;
    __syncthreads();
    for (int off = 1; off < 256; off <<= 1) {
        const uint32_t v = (tid >= off) ? S[tid - off] : ID;
        __syncthreads();
        if (tid >= off) S[tid] = map_comp(S[tid], v);
        __syncthreads();
    }
    const uint32_t pre = (tid == 0) ? ID : S[tid - 1];
    uint32_t s = (pre >> 24) & 0xFFu;   // prefix applied to initial state 3
    uint8_t* er = entries + m * NCH + tid * 16;
#pragma unroll
    for (int j = 0; j < 16; ++j) {
        er[j] = (uint8_t)s;
        s = (maps[j] >> (8 * s)) & 0xFFu;
    }
}

// ---------------- pass C: re-scan with known entry state; in-place y -> tanh
__global__ __launch_bounds__(256) void scan_pass_c(
    float* yo, const float* __restrict__ sp, const float* __restrict__ pwv,
    const uint8_t* __restrict__ entries)
{
    const int gid = blockIdx.x * 256 + threadIdx.x;
    const int m = gid >> 12;
    const int c = gid & (NCH - 1);
    const float pw = pwv[m];
    const float spv = sp[m];
    const uint32_t s = entries[m * NCH + c];
    float p = (s == 3u) ? spv : ((float)(int)s - 1.0f);
    float* row = yo + (size_t)m * OUT_W + 1 + c * CL;
    if (c == 0) yo[(size_t)m * OUT_W] = spv;
    const int limit0 = TY_LEN - c * CL;
    const int limit = limit0 < CL ? limit0 : CL;
    int j = 0;
    for (; j + 4 <= limit; j += 4) {
        const float4 h = *reinterpret_cast<const float4*>(row + j);
        float a;
        a = fmaf(p, pw, h.x); row[j+0] = tanhf(a); p = sgnf(a);
        a = fmaf(p, pw, h.y); row[j+1] = tanhf(a); p = sgnf(a);
        a = fmaf(p, pw, h.z); row[j+2] = tanhf(a); p = sgnf(a);
        a = fmaf(p, pw, h.w); row[j+3] = tanhf(a); p = sgnf(a);
    }
    for (; j < limit; ++j) {
        const float a = fmaf(p, pw, row[j]);
        row[j] = tanhf(a);
        p = sgnf(a);
    }
}

extern "C" void kernel_launch(void* const* d_in, const int* in_sizes, int n_in,
                              void* d_out, int out_size, void* d_ws, size_t ws_size,
                              hipStream_t stream)
{
    const float* x   = (const float*)d_in[0];
    const float* spv = (const float*)d_in[1];
    const float* w   = (const float*)d_in[2];
    const float* b   = (const float*)d_in[3];
    const float* pw  = (const float*)d_in[4];
    float* out = (float*)d_out;

    // workspace: wT 64 KiB | trans 512 KiB | entries 128 KiB
    uint8_t* ws = (uint8_t*)d_ws;
    float*    wT      = (float*)ws;
    uint32_t* trans   = (uint32_t*)(ws + 65536);
    uint8_t*  entries = (uint8_t*)(ws + 65536 + 524288);

    const int conv_blocks = (TY_LEN + TO - 1) / TO;   // 2048
    wtrans_kernel<<<64, 256, 0, stream>>>(w, wT);
    conv_kernel<<<conv_blocks, 256, 0, stream>>>(x, wT, b, out);
    scan_pass_a<<<(NM * NCH) / 256, 256, 0, stream>>>(out, spv, pw, trans);
    scan_pass_b<<<NM, 256, 0, stream>>>(trans, entries);
    scan_pass_c<<<(NM * NCH) / 256, 256, 0, stream>>>(out, spv, pw, entries);
}

// Round 10
// 546.243 us; speedup vs baseline: 1.2528x; 1.2528x over previous
//
#include <hip/hip_runtime.h>
#include <stdint.h>

#define T_LEN    1048576
#define TY_LEN   1048561
#define OUT_W    1048562
#define NM       32
#define WIN      16
#define NCH      4096
#define CL       256
#define CBT      192    // conv block threads = outputs per block
#define XS_W     208    // 192 + 15 halo + pad; 32*208*4 = 26624 B -> 6 blocks/CU
#define NF4      52     // XS_W/4 float4s per channel

__device__ inline float sgnf(float a){
    return (a > 0.0f) ? 1.0f : ((a < 0.0f) ? -1.0f : 0.0f);
}

// ---------------- transpose w[o][i][h] -> wT[h][i][o] (o fastest, for
// wave-uniform consecutive scalar loads in the conv inner loop)
__global__ void wtrans_kernel(const float* __restrict__ w, float* __restrict__ wT){
    const int idx = blockIdx.x * 256 + threadIdx.x;
    if (idx >= NM * NM * WIN) return;
    const int o = idx / (NM * WIN);
    const int r = idx - o * (NM * WIN);
    const int i = r / WIN;
    const int h = r - i * WIN;
    wT[(h * NM + i) * NM + o] = w[idx];
}

// ---------------- conv, XLA-CPU-faithful order (h-major, i-minor, bias last):
// per output (o,t): acc = 0; for h: for i: acc = fmaf(w[o][i][h], x[i][t+h], acc)
// 192-thread blocks, 26.6 KiB LDS -> 6 blocks/CU (4.5 waves/SIMD) for latency
// hiding. Per-accumulator FMA order is bit-identical to the passing kernels.
__global__ __launch_bounds__(192) void conv_kernel(
    const float* __restrict__ x, const float* __restrict__ wT,
    const float* __restrict__ b, float* __restrict__ out)
{
    __shared__ float xs[NM * XS_W];
    const int base = blockIdx.x * CBT;
    // float4 staging: base = bid*192 -> 768 B aligned; rows T_LEN-aligned.
    for (int idx = threadIdx.x; idx < NM * NF4; idx += CBT) {
        const int i = idx / NF4;
        const int q = idx - i * NF4;
        const int t0 = base + q * 4;
        float4 v;
        if (t0 + 3 < T_LEN) {
            v = *reinterpret_cast<const float4*>(x + (size_t)i * T_LEN + t0);
        } else {
            v.x = (t0 + 0 < T_LEN) ? x[(size_t)i * T_LEN + t0 + 0] : 0.0f;
            v.y = (t0 + 1 < T_LEN) ? x[(size_t)i * T_LEN + t0 + 1] : 0.0f;
            v.z = (t0 + 2 < T_LEN) ? x[(size_t)i * T_LEN + t0 + 2] : 0.0f;
            v.w = (t0 + 3 < T_LEN) ? x[(size_t)i * T_LEN + t0 + 3] : 0.0f;
        }
        *reinterpret_cast<float4*>(&xs[i * XS_W + q * 4]) = v;
    }
    __syncthreads();
    const int tl = threadIdx.x;
    float acc[NM];
#pragma unroll
    for (int o = 0; o < NM; ++o) acc[o] = 0.0f;
#pragma unroll 1
    for (int h = 0; h < WIN; h += 2) {
        float xv0[NM], xv1[NM];
#pragma unroll
        for (int i = 0; i < NM; ++i) {
            xv0[i] = xs[i * XS_W + tl + h];       // adjacent dwords ->
            xv1[i] = xs[i * XS_W + tl + h + 1];   // ds_read2_b32 merge
        }
#pragma unroll
        for (int i = 0; i < NM; ++i) {
            const float* wrow = wT + (h * NM + i) * NM;   // lane-uniform s_load
#pragma unroll
            for (int o = 0; o < NM; ++o)
                acc[o] = fmaf(wrow[o], xv0[i], acc[o]);
        }
#pragma unroll
        for (int i = 0; i < NM; ++i) {
            const float* wrow = wT + ((h + 1) * NM + i) * NM;
#pragma unroll
            for (int o = 0; o < NM; ++o)
                acc[o] = fmaf(wrow[o], xv1[i], acc[o]);
        }
    }
    const int t = base + tl;
    if (t < TY_LEN) {
#pragma unroll
        for (int o = 0; o < NM; ++o)
            out[(size_t)o * OUT_W + 1 + t] = acc[o] + b[o];
    }
}

// ---------------- pass A: per-(market, chunk) 4-candidate transition map
// candidates: {-1, 0, +1, start_pos}; exit quantized to {0,1,2} = {-1,0,+1}
__global__ __launch_bounds__(256) void scan_pass_a(
    const float* __restrict__ yb, const float* __restrict__ sp,
    const float* __restrict__ pwv, uint32_t* __restrict__ trans)
{
    const int gid = blockIdx.x * 256 + threadIdx.x;
    const int m = gid >> 12;
    const int c = gid & (NCH - 1);
    const float pw = pwv[m];
    float p0 = -1.0f, p1 = 0.0f, p2 = 1.0f, p3 = sp[m];
    const float* hr = yb + (size_t)m * OUT_W + 1 + c * CL;
    const int limit0 = TY_LEN - c * CL;
    const int limit = limit0 < CL ? limit0 : CL;
    int j = 0;
    for (; j + 4 <= limit; j += 4) {
        const float4 h = *reinterpret_cast<const float4*>(hr + j);
#define STEPA(hv) { const float hv_ = (hv); \
        p0 = sgnf(fmaf(p0, pw, hv_)); \
        p1 = sgnf(fmaf(p1, pw, hv_)); \
        p2 = sgnf(fmaf(p2, pw, hv_)); \
        p3 = sgnf(fmaf(p3, pw, hv_)); }
        STEPA(h.x); STEPA(h.y); STEPA(h.z); STEPA(h.w);
    }
    for (; j < limit; ++j) { STEPA(hr[j]); }
#undef STEPA
    const uint32_t e0 = (uint32_t)((int)p0 + 1);
    const uint32_t e1 = (uint32_t)((int)p1 + 1);
    const uint32_t e2 = (uint32_t)((int)p2 + 1);
    const uint32_t e3 = (uint32_t)((int)p3 + 1);
    trans[m * NCH + c] = e0 | (e1 << 8) | (e2 << 16) | (e3 << 24);
}

// ---------------- pass B: compose maps per market, emit entry state per chunk
__device__ inline uint32_t map_comp(uint32_t f, uint32_t g){
    uint32_t r = 0;
#pragma unroll
    for (int k = 0; k < 4; ++k) {
        const uint32_t s = (g >> (8 * k)) & 0xFFu;
        const uint32_t o = (f >> (8 * s)) & 0xFFu;
        r |= o << (8 * k);
    }
    return r;
}

__global__ __launch_bounds__(256) void scan_pass_b(
    const uint32_t* __restrict__ trans, uint8_t* __restrict__ entries)
{
    const uint32_t ID = 0x03020100u;   // identity; state 3 = raw start_pos
    const int m = blockIdx.x;
    const int tid = threadIdx.x;
    __shared__ uint32_t S[256];
    uint32_t maps[16];
    uint32_t seg = ID;
    const uint32_t* tr = trans + m * NCH + tid * 16;
#pragma unroll
    for (int j = 0; j < 16; ++j) { maps[j] = tr[j]; seg = map_comp(maps[j], seg); }
    S[tid] = seg;
    __syncthreads();
    for (int off = 1; off < 256; off <<= 1) {
        const uint32_t v = (tid >= off) ? S[tid - off] : ID;
        __syncthreads();
        if (tid >= off) S[tid] = map_comp(S[tid], v);
        __syncthreads();
    }
    const uint32_t pre = (tid == 0) ? ID : S[tid - 1];
    uint32_t s = (pre >> 24) & 0xFFu;   // prefix applied to initial state 3
    uint8_t* er = entries + m * NCH + tid * 16;
#pragma unroll
    for (int j = 0; j < 16; ++j) {
        er[j] = (uint8_t)s;
        s = (maps[j] >> (8 * s)) & 0xFFu;
    }
}

// ---------------- pass C: re-scan with known entry state; in-place y -> tanh
__global__ __launch_bounds__(256) void scan_pass_c(
    float* yo, const float* __restrict__ sp, const float* __restrict__ pwv,
    const uint8_t* __restrict__ entries)
{
    const int gid = blockIdx.x * 256 + threadIdx.x;
    const int m = gid >> 12;
    const int c = gid & (NCH - 1);
    const float pw = pwv[m];
    const float spv = sp[m];
    const uint32_t s = entries[m * NCH + c];
    float p = (s == 3u) ? spv : ((float)(int)s - 1.0f);
    float* row = yo + (size_t)m * OUT_W + 1 + c * CL;
    if (c == 0) yo[(size_t)m * OUT_W] = spv;
    const int limit0 = TY_LEN - c * CL;
    const int limit = limit0 < CL ? limit0 : CL;
    int j = 0;
    for (; j + 4 <= limit; j += 4) {
        const float4 h = *reinterpret_cast<const float4*>(row + j);
        float a;
        a = fmaf(p, pw, h.x); row[j+0] = tanhf(a); p = sgnf(a);
        a = fmaf(p, pw, h.y); row[j+1] = tanhf(a); p = sgnf(a);
        a = fmaf(p, pw, h.z); row[j+2] = tanhf(a); p = sgnf(a);
        a = fmaf(p, pw, h.w); row[j+3] = tanhf(a); p = sgnf(a);
    }
    for (; j < limit; ++j) {
        const float a = fmaf(p, pw, row[j]);
        row[j] = tanhf(a);
        p = sgnf(a);
    }
}

extern "C" void kernel_launch(void* const* d_in, const int* in_sizes, int n_in,
                              void* d_out, int out_size, void* d_ws, size_t ws_size,
                              hipStream_t stream)
{
    const float* x   = (const float*)d_in[0];
    const float* spv = (const float*)d_in[1];
    const float* w   = (const float*)d_in[2];
    const float* b   = (const float*)d_in[3];
    const float* pw  = (const float*)d_in[4];
    float* out = (float*)d_out;

    // workspace: wT 64 KiB | trans 512 KiB | entries 128 KiB
    uint8_t* ws = (uint8_t*)d_ws;
    float*    wT      = (float*)ws;
    uint32_t* trans   = (uint32_t*)(ws + 65536);
    uint8_t*  entries = (uint8_t*)(ws + 65536 + 524288);

    const int conv_blocks = (TY_LEN + CBT - 1) / CBT;   // 5461
    wtrans_kernel<<<64, 256, 0, stream>>>(w, wT);
    conv_kernel<<<conv_blocks, CBT, 0, stream>>>(x, wT, b, out);
    scan_pass_a<<<(NM * NCH) / 256, 256, 0, stream>>>(out, spv, pw, trans);
    scan_pass_b<<<NM, 256, 0, stream>>>(trans, entries);
    scan_pass_c<<<(NM * NCH) / 256, 256, 0, stream>>>(out, spv, pw, entries);
}